// Round 2
// baseline (1400.048 us; speedup 1.0000x reference)
//
#include <hip/hip_runtime.h>
#include <stdint.h>

#define NC 5
#define IMAXP1 33
#define SEGS (NC * IMAXP1)      // 165
#define REP 8                   // sub-bank replication factor
#define HSTRIDE (SEGS * REP)    // 1320 floats per wave-private histogram
#define HW_ (512 * 512)
#define IGNORE_L 255
#define CHUNK 65536             // pixels per segsum block

// ---------------- Pass 1: seg ids + counts ----------------
__global__ __launch_bounds__(256) void seg_count_kernel(
    const int* __restrict__ labels, const int* __restrict__ indexes,
    uint8_t* __restrict__ seg, unsigned* __restrict__ counts,
    int pix_per_block) {
  __shared__ unsigned hist[SEGS];
  for (int i = threadIdx.x; i < SEGS; i += blockDim.x) hist[i] = 0u;
  __syncthreads();

  const long long base = (long long)blockIdx.x * pix_per_block;
  const int b = (int)(base / HW_);          // pix_per_block divides HW_
  const int nvec = pix_per_block / 4;
  const int4* lab4 = (const int4*)(labels + base);
  const int4* idx4 = (const int4*)(indexes + base);
  uchar4* seg4 = (uchar4*)(seg + base);

  for (int k = threadIdx.x; k < nvec; k += blockDim.x) {
    int4 l = lab4[k];
    int4 ix = idx4[k];
    int s0 = (l.x == IGNORE_L) ? 0 : l.x * IMAXP1 + ix.x;
    int s1 = (l.y == IGNORE_L) ? 0 : l.y * IMAXP1 + ix.y;
    int s2 = (l.z == IGNORE_L) ? 0 : l.z * IMAXP1 + ix.z;
    int s3 = (l.w == IGNORE_L) ? 0 : l.w * IMAXP1 + ix.w;
    uchar4 sv;
    sv.x = (unsigned char)s0; sv.y = (unsigned char)s1;
    sv.z = (unsigned char)s2; sv.w = (unsigned char)s3;
    seg4[k] = sv;
    atomicAdd(&hist[s0], 1u);
    atomicAdd(&hist[s1], 1u);
    atomicAdd(&hist[s2], 1u);
    atomicAdd(&hist[s3], 1u);
  }
  __syncthreads();
  for (int i = threadIdx.x; i < SEGS; i += blockDim.x)
    if (hist[i]) atomicAdd(&counts[b * SEGS + i], hist[i]);
}

// ---------------- Pass 2: segment sums of the feature tensor ----------------
// One block per (b, d, pixel-chunk). Streams the contiguous (b,d) plane chunk
// with float4 loads; scatter-adds into per-wave-private, 8-way sub-bank
// replicated LDS histograms (kills same-address atomic RMW serialization).
__global__ __launch_bounds__(256) void segsum_kernel(
    const float* __restrict__ feat, const uint8_t* __restrict__ seg,
    float* __restrict__ sums, int D, int chunks_per_plane) {
  __shared__ float hist[4 * HSTRIDE];       // 4 waves x 165 segs x 8 reps
  const int bid = blockIdx.x;
  const int chunk = bid % chunks_per_plane;
  const int bd = bid / chunks_per_plane;
  const int d = bd % D;
  const int b = bd / D;

  for (int i = threadIdx.x; i < 4 * HSTRIDE; i += 256) hist[i] = 0.f;
  __syncthreads();

  float* __restrict__ h =
      hist + (threadIdx.x >> 6) * HSTRIDE + (threadIdx.x & (REP - 1));
  const float4* f4 =
      (const float4*)(feat + (size_t)(b * D + d) * HW_ + (size_t)chunk * CHUNK);
  const uchar4* s4 =
      (const uchar4*)(seg + (size_t)b * HW_ + (size_t)chunk * CHUNK);

  // 1-deep software pipeline: one load pair always in flight
  float4 v = f4[threadIdx.x];
  uchar4 sv = s4[threadIdx.x];
  for (int k = threadIdx.x + 256; k < CHUNK / 4; k += 256) {
    float4 vn = f4[k];
    uchar4 sn = s4[k];
    atomicAdd(h + (int)sv.x * REP, v.x);
    atomicAdd(h + (int)sv.y * REP, v.y);
    atomicAdd(h + (int)sv.z * REP, v.z);
    atomicAdd(h + (int)sv.w * REP, v.w);
    v = vn;
    sv = sn;
  }
  atomicAdd(h + (int)sv.x * REP, v.x);
  atomicAdd(h + (int)sv.y * REP, v.y);
  atomicAdd(h + (int)sv.z * REP, v.z);
  atomicAdd(h + (int)sv.w * REP, v.w);
  __syncthreads();

  for (int s = threadIdx.x; s < SEGS; s += 256) {
    float t = 0.f;
    #pragma unroll
    for (int w = 0; w < 4; ++w)
      #pragma unroll
      for (int r = 0; r < REP; ++r) t += hist[w * HSTRIDE + s * REP + r];
    if (t != 0.f)
      atomicAdd(&sums[((size_t)b * SEGS + s) * D + d], t);
  }
}

// ---------------- Pass 3: per-(image,class) pairwise loss ----------------
__global__ __launch_bounds__(256) void pairloss_kernel(
    const float* __restrict__ sums, const unsigned* __restrict__ counts,
    float* __restrict__ loss_sum, unsigned* __restrict__ nvalid, int D) {
  const int b = blockIdx.x / NC;
  const int c = blockIdx.x % NC;

  __shared__ float sh_mean[32 * 128];
  __shared__ float sh_cnt[IMAXP1];
  __shared__ int list[IMAXP1];
  __shared__ int Ksh;
  __shared__ uchar2 pairs[32 * 31 / 2];
  __shared__ double wred[4];

  if (threadIdx.x == 0) {
    int K = 0;
    for (int i = 1; i < IMAXP1; ++i) {   // slot 0 (ignore key) excluded
      unsigned cnt = counts[b * SEGS + c * IMAXP1 + i];
      if (cnt >= 2u) {                   // singleton segments excluded
        list[K] = i;
        sh_cnt[K] = (float)cnt;
        ++K;
      }
    }
    Ksh = K;
    int p = 0;
    for (int i = 0; i < K; ++i)
      for (int j = i + 1; j < K; ++j) {
        pairs[p].x = (unsigned char)i;
        pairs[p].y = (unsigned char)j;
        ++p;
      }
  }
  __syncthreads();
  const int K = Ksh;
  if (K == 0) return;                    // has=0 for this (b,c)

  // stage means of included instances in LDS
  for (int idx = threadIdx.x; idx < K * D; idx += blockDim.x) {
    int k = idx / 128, d = idx % 128;    // D==128
    int s = c * IMAXP1 + list[k];
    sh_mean[k * 128 + d] =
        sums[((size_t)b * SEGS + s) * D + d] / sh_cnt[k];
  }
  __syncthreads();

  const int npairs = K * (K - 1) / 2;
  const int total = npairs * 128;
  float local = 0.f;
  for (int idx = threadIdx.x; idx < total; idx += blockDim.x) {
    int p = idx >> 7, d = idx & 127;
    int i = pairs[p].x, j = pairs[p].y;
    local += fabsf(sh_mean[i * 128 + d] - sh_mean[j * 128 + d]);
  }

  double v = (double)local;
  #pragma unroll
  for (int off = 32; off; off >>= 1) v += __shfl_down(v, off, 64);
  const int wave = threadIdx.x >> 6;
  if ((threadIdx.x & 63) == 0) wred[wave] = v;
  __syncthreads();
  if (threadIdx.x == 0) {
    double ssum = 2.0 * (wred[0] + wred[1] + wred[2] + wred[3]);
    double ret = ssum / ((double)K * (double)K * (double)D);
    double loss = (ret < 1.0) ? 0.5 * ret * ret : ret - 0.5;
    atomicAdd(loss_sum, (float)loss);
    atomicAdd(nvalid, 1u);
  }
}

// ---------------- Pass 4: finalize ----------------
__global__ void finalize_kernel(const float* __restrict__ loss_sum,
                                const unsigned* __restrict__ nvalid,
                                float* __restrict__ out, int B) {
  if (threadIdx.x == 0) {
    unsigned n = *nvalid;
    out[0] = n ? (*loss_sum / (float)n) / (float)B : 0.f;
  }
}

extern "C" void kernel_launch(void* const* d_in, const int* in_sizes, int n_in,
                              void* d_out, int out_size, void* d_ws,
                              size_t ws_size, hipStream_t stream) {
  const float* feat = (const float*)d_in[0];
  const int* labels = (const int*)d_in[1];
  const int* indexes = (const int*)d_in[2];

  const int npix_total = in_sizes[1];          // B*H*W
  const int B = npix_total / HW_;              // 8
  const int D = in_sizes[0] / npix_total;      // 128

  // workspace layout: [seg bytes][sums f32][counts u32][loss f32][n u32]
  uint8_t* seg = (uint8_t*)d_ws;
  size_t off = ((size_t)npix_total + 255) & ~(size_t)255;
  float* sums = (float*)((char*)d_ws + off);
  size_t sums_bytes = (size_t)B * SEGS * D * sizeof(float);
  unsigned* counts = (unsigned*)((char*)d_ws + off + sums_bytes);
  size_t counts_bytes = (size_t)B * SEGS * sizeof(unsigned);
  float* loss_sum = (float*)((char*)d_ws + off + sums_bytes + counts_bytes);
  unsigned* nvalid = (unsigned*)(loss_sum + 1);

  // zero the accumulator region (sums..nvalid) every call
  hipMemsetAsync(sums, 0, sums_bytes + counts_bytes + 2 * sizeof(unsigned),
                 stream);

  const int pix_per_block = 4096;              // divides HW_
  seg_count_kernel<<<npix_total / pix_per_block, 256, 0, stream>>>(
      labels, indexes, seg, counts, pix_per_block);

  const int cpp = HW_ / CHUNK;                 // 4 chunks per plane
  segsum_kernel<<<B * D * cpp, 256, 0, stream>>>(feat, seg, sums, D, cpp);

  pairloss_kernel<<<B * NC, 256, 0, stream>>>(sums, counts, loss_sum, nvalid,
                                              D);
  finalize_kernel<<<1, 64, 0, stream>>>(loss_sum, nvalid, (float*)d_out, B);
}

// Round 3
// 426.023 us; speedup vs baseline: 3.2863x; 3.2863x over previous
//
#include <hip/hip_runtime.h>
#include <stdint.h>

#define NC 5
#define IMAXP1 33
#define SEGS 165            // 5 * 33
#define SEGS_PAD 192        // 6 M-tiles of 32
#define MT 6
#define HW_ (512 * 512)
#define IGNORE_L 255
#define KCHUNK 2048         // pixels per segsum block
#define KSTEPS (KCHUNK / 16)

typedef __attribute__((ext_vector_type(8))) short short8v;
typedef __attribute__((ext_vector_type(16))) float f32x16;

__device__ inline unsigned short bf16_rne(float f) {
  unsigned u = __builtin_bit_cast(unsigned, f);
  u += 0x7FFFu + ((u >> 16) & 1u);
  return (unsigned short)(u >> 16);
}

// ---------------- Pass 1: seg ids + counts ----------------
__global__ __launch_bounds__(256) void seg_count_kernel(
    const int* __restrict__ labels, const int* __restrict__ indexes,
    uint8_t* __restrict__ seg, unsigned* __restrict__ counts,
    int pix_per_block) {
  __shared__ unsigned hist[SEGS];
  for (int i = threadIdx.x; i < SEGS; i += blockDim.x) hist[i] = 0u;
  __syncthreads();

  const long long base = (long long)blockIdx.x * pix_per_block;
  const int b = (int)(base / HW_);
  const int nvec = pix_per_block / 4;
  const int4* lab4 = (const int4*)(labels + base);
  const int4* idx4 = (const int4*)(indexes + base);
  uchar4* seg4 = (uchar4*)(seg + base);

  for (int k = threadIdx.x; k < nvec; k += blockDim.x) {
    int4 l = lab4[k];
    int4 ix = idx4[k];
    int s0 = (l.x == IGNORE_L) ? 0 : l.x * IMAXP1 + ix.x;
    int s1 = (l.y == IGNORE_L) ? 0 : l.y * IMAXP1 + ix.y;
    int s2 = (l.z == IGNORE_L) ? 0 : l.z * IMAXP1 + ix.z;
    int s3 = (l.w == IGNORE_L) ? 0 : l.w * IMAXP1 + ix.w;
    uchar4 sv;
    sv.x = (unsigned char)s0; sv.y = (unsigned char)s1;
    sv.z = (unsigned char)s2; sv.w = (unsigned char)s3;
    seg4[k] = sv;
    atomicAdd(&hist[s0], 1u);
    atomicAdd(&hist[s1], 1u);
    atomicAdd(&hist[s2], 1u);
    atomicAdd(&hist[s3], 1u);
  }
  __syncthreads();
  for (int i = threadIdx.x; i < SEGS; i += blockDim.x)
    if (hist[i]) atomicAdd(&counts[b * SEGS + i], hist[i]);
}

// ---------------- Pass 2: segment sums via one-hot MFMA GEMM ----------------
// sums[s,d] += sum_p onehot[s,p] * feat[p,d], computed as bf16 split-float
// MFMA (hi+lo) with f32 accumulation. One block per (image, 2048-pixel chunk).
// Wave w owns channels [w*32, w*32+32); all 6 seg M-tiles accumulated in regs.
__global__ __launch_bounds__(256) void segsum_mfma_kernel(
    const float* __restrict__ feat, const uint8_t* __restrict__ seg,
    float* __restrict__ sums, int chunks_per_img) {
  __shared__ unsigned long long sseg8[KCHUNK / 8];
  const int b = blockIdx.x / chunks_per_img;
  const int chunk = blockIdx.x % chunks_per_img;
  const int pbase = chunk * KCHUNK;

  // stage seg bytes for this chunk (one u64 per thread)
  const unsigned long long* gseg8 =
      (const unsigned long long*)(seg + (size_t)b * HW_ + pbase);
  sseg8[threadIdx.x] = gseg8[threadIdx.x];
  __syncthreads();

  const int l = threadIdx.x & 63;
  const int w = threadIdx.x >> 6;
  const int lane31 = l & 31;
  const int hi = l >> 5;
  const int ch = w * 32 + lane31;

  const float* fp = feat + ((size_t)b * 128 + ch) * HW_ + pbase + hi * 8;
  const uint8_t* sp = (const uint8_t*)sseg8 + hi * 8;

  f32x16 acc[MT];
  #pragma unroll
  for (int m = 0; m < MT; ++m) acc[m] = (f32x16)(0.f);

  for (int k = 0; k < KSTEPS; ++k) {
    unsigned long long sb = *(const unsigned long long*)(sp + k * 16);
    float4 v0 = *(const float4*)(fp + k * 16);
    float4 v1 = *(const float4*)(fp + k * 16 + 4);
    float f[8] = {v0.x, v0.y, v0.z, v0.w, v1.x, v1.y, v1.z, v1.w};

    union { unsigned short us[8]; short8v v; } bhi, blo;
    #pragma unroll
    for (int e = 0; e < 8; ++e) {
      unsigned short h = bf16_rne(f[e]);
      float fh = __builtin_bit_cast(float, (unsigned)h << 16);
      bhi.us[e] = h;
      blo.us[e] = bf16_rne(f[e] - fh);
    }

    #pragma unroll
    for (int m = 0; m < MT; ++m) {
      union { unsigned short us[8]; short8v v; } a;
      #pragma unroll
      for (int e = 0; e < 8; ++e) {
        unsigned sv = (unsigned)((sb >> (8 * e)) & 0xFFull);
        a.us[e] = (sv == (unsigned)(m * 32 + lane31)) ? (unsigned short)0x3F80
                                                      : (unsigned short)0;
      }
      acc[m] =
          __builtin_amdgcn_mfma_f32_32x32x16_bf16(a.v, bhi.v, acc[m], 0, 0, 0);
      acc[m] =
          __builtin_amdgcn_mfma_f32_32x32x16_bf16(a.v, blo.v, acc[m], 0, 0, 0);
    }
  }

  // epilogue: C/D layout col=lane&31, row=(reg&3)+8*(reg>>2)+4*(lane>>5)
  #pragma unroll
  for (int m = 0; m < MT; ++m) {
    #pragma unroll
    for (int r = 0; r < 16; ++r) {
      int s = m * 32 + (r & 3) + 8 * (r >> 2) + 4 * hi;
      float v = acc[m][r];
      if (v != 0.f)
        atomicAdd(&sums[((size_t)b * SEGS_PAD + s) * 128 + ch], v);
    }
  }
}

// ---------------- Pass 3: per-(image,class) pairwise loss ----------------
__global__ __launch_bounds__(256) void pairloss_kernel(
    const float* __restrict__ sums, const unsigned* __restrict__ counts,
    float* __restrict__ loss_sum, unsigned* __restrict__ nvalid, int D) {
  const int b = blockIdx.x / NC;
  const int c = blockIdx.x % NC;

  __shared__ float sh_mean[32 * 128];
  __shared__ float sh_cnt[IMAXP1];
  __shared__ int list[IMAXP1];
  __shared__ int Ksh;
  __shared__ uchar2 pairs[32 * 31 / 2];
  __shared__ double wred[4];

  if (threadIdx.x == 0) {
    int K = 0;
    for (int i = 1; i < IMAXP1; ++i) {   // slot 0 (ignore key) excluded
      unsigned cnt = counts[b * SEGS + c * IMAXP1 + i];
      if (cnt >= 2u) {                   // singleton segments excluded
        list[K] = i;
        sh_cnt[K] = (float)cnt;
        ++K;
      }
    }
    Ksh = K;
    int p = 0;
    for (int i = 0; i < K; ++i)
      for (int j = i + 1; j < K; ++j) {
        pairs[p].x = (unsigned char)i;
        pairs[p].y = (unsigned char)j;
        ++p;
      }
  }
  __syncthreads();
  const int K = Ksh;
  if (K == 0) return;

  for (int idx = threadIdx.x; idx < K * D; idx += blockDim.x) {
    int k = idx / 128, d = idx % 128;    // D==128
    int s = c * IMAXP1 + list[k];
    sh_mean[k * 128 + d] =
        sums[((size_t)b * SEGS_PAD + s) * D + d] / sh_cnt[k];
  }
  __syncthreads();

  const int npairs = K * (K - 1) / 2;
  const int total = npairs * 128;
  float local = 0.f;
  for (int idx = threadIdx.x; idx < total; idx += blockDim.x) {
    int p = idx >> 7, d = idx & 127;
    int i = pairs[p].x, j = pairs[p].y;
    local += fabsf(sh_mean[i * 128 + d] - sh_mean[j * 128 + d]);
  }

  double v = (double)local;
  #pragma unroll
  for (int off = 32; off; off >>= 1) v += __shfl_down(v, off, 64);
  const int wave = threadIdx.x >> 6;
  if ((threadIdx.x & 63) == 0) wred[wave] = v;
  __syncthreads();
  if (threadIdx.x == 0) {
    double ssum = 2.0 * (wred[0] + wred[1] + wred[2] + wred[3]);
    double ret = ssum / ((double)K * (double)K * (double)D);
    double loss = (ret < 1.0) ? 0.5 * ret * ret : ret - 0.5;
    atomicAdd(loss_sum, (float)loss);
    atomicAdd(nvalid, 1u);
  }
}

// ---------------- Pass 4: finalize ----------------
__global__ void finalize_kernel(const float* __restrict__ loss_sum,
                                const unsigned* __restrict__ nvalid,
                                float* __restrict__ out, int B) {
  if (threadIdx.x == 0) {
    unsigned n = *nvalid;
    out[0] = n ? (*loss_sum / (float)n) / (float)B : 0.f;
  }
}

extern "C" void kernel_launch(void* const* d_in, const int* in_sizes, int n_in,
                              void* d_out, int out_size, void* d_ws,
                              size_t ws_size, hipStream_t stream) {
  const float* feat = (const float*)d_in[0];
  const int* labels = (const int*)d_in[1];
  const int* indexes = (const int*)d_in[2];

  const int npix_total = in_sizes[1];          // B*H*W
  const int B = npix_total / HW_;              // 8
  const int D = in_sizes[0] / npix_total;      // 128

  // workspace: [seg bytes][sums f32 (SEGS_PAD)][counts u32][loss f32][n u32]
  uint8_t* seg = (uint8_t*)d_ws;
  size_t off = ((size_t)npix_total + 255) & ~(size_t)255;
  float* sums = (float*)((char*)d_ws + off);
  size_t sums_bytes = (size_t)B * SEGS_PAD * D * sizeof(float);
  unsigned* counts = (unsigned*)((char*)d_ws + off + sums_bytes);
  size_t counts_bytes = (size_t)B * SEGS * sizeof(unsigned);
  float* loss_sum = (float*)((char*)d_ws + off + sums_bytes + counts_bytes);
  unsigned* nvalid = (unsigned*)(loss_sum + 1);

  hipMemsetAsync(sums, 0, sums_bytes + counts_bytes + 2 * sizeof(unsigned),
                 stream);

  const int pix_per_block = 4096;
  seg_count_kernel<<<npix_total / pix_per_block, 256, 0, stream>>>(
      labels, indexes, seg, counts, pix_per_block);

  const int cpi = HW_ / KCHUNK;                // 128 chunks per image
  segsum_mfma_kernel<<<B * cpi, 256, 0, stream>>>(feat, seg, sums, cpi);

  pairloss_kernel<<<B * NC, 256, 0, stream>>>(sums, counts, loss_sum, nvalid,
                                              D);
  finalize_kernel<<<1, 64, 0, stream>>>(loss_sum, nvalid, (float*)d_out, B);
}

// Round 4
// 394.477 us; speedup vs baseline: 3.5491x; 1.0800x over previous
//
#include <hip/hip_runtime.h>
#include <stdint.h>

#define NC 5
#define IMAXP1 33
#define SEGS 165            // 5 * 33
#define SEGS_PAD 192        // 6 M-tiles of 32
#define MT 6
#define HW_ (512 * 512)
#define IGNORE_L 255
#define KCHUNK 2048         // pixels per segsum block
#define KSTEPS (KCHUNK / 16)

typedef __attribute__((ext_vector_type(8))) short short8v;
typedef __attribute__((ext_vector_type(16))) float f32x16;
typedef __attribute__((ext_vector_type(2))) unsigned short u16x2;
typedef __attribute__((ext_vector_type(2))) float float2v;
typedef __attribute__((ext_vector_type(2))) __bf16 bf16x2;

// ---------------- Pass 1: seg ids + counts ----------------
__global__ __launch_bounds__(256) void seg_count_kernel(
    const int* __restrict__ labels, const int* __restrict__ indexes,
    uint8_t* __restrict__ seg, unsigned* __restrict__ counts,
    int pix_per_block) {
  __shared__ unsigned hist[SEGS];
  for (int i = threadIdx.x; i < SEGS; i += blockDim.x) hist[i] = 0u;
  __syncthreads();

  const long long base = (long long)blockIdx.x * pix_per_block;
  const int b = (int)(base / HW_);
  const int nvec = pix_per_block / 4;
  const int4* lab4 = (const int4*)(labels + base);
  const int4* idx4 = (const int4*)(indexes + base);
  uchar4* seg4 = (uchar4*)(seg + base);

  for (int k = threadIdx.x; k < nvec; k += blockDim.x) {
    int4 l = lab4[k];
    int4 ix = idx4[k];
    int s0 = (l.x == IGNORE_L) ? 0 : l.x * IMAXP1 + ix.x;
    int s1 = (l.y == IGNORE_L) ? 0 : l.y * IMAXP1 + ix.y;
    int s2 = (l.z == IGNORE_L) ? 0 : l.z * IMAXP1 + ix.z;
    int s3 = (l.w == IGNORE_L) ? 0 : l.w * IMAXP1 + ix.w;
    uchar4 sv;
    sv.x = (unsigned char)s0; sv.y = (unsigned char)s1;
    sv.z = (unsigned char)s2; sv.w = (unsigned char)s3;
    seg4[k] = sv;
    atomicAdd(&hist[s0], 1u);
    atomicAdd(&hist[s1], 1u);
    atomicAdd(&hist[s2], 1u);
    atomicAdd(&hist[s3], 1u);
  }
  __syncthreads();
  for (int i = threadIdx.x; i < SEGS; i += blockDim.x)
    if (hist[i]) atomicAdd(&counts[b * SEGS + i], hist[i]);
}

// ---------------- Pass 2: segment sums via one-hot MFMA GEMM ----------------
// sums[s,d] += sum_p onehot[s,p] * feat[p,d]; bf16 split-float (hi+lo) MFMA
// with f32 accumulation. One block per (image, 2048-pixel chunk); wave w owns
// channels [w*32, w*32+32). Packed-u16 one-hot build + v_cvt_pk_bf16_f32.
__global__ __launch_bounds__(256) void segsum_mfma_kernel(
    const float* __restrict__ feat, const uint8_t* __restrict__ seg,
    float* __restrict__ sums, int chunks_per_img) {
  __shared__ unsigned long long sseg8[KCHUNK / 8];
  const int b = blockIdx.x / chunks_per_img;
  const int chunk = blockIdx.x % chunks_per_img;
  const int pbase = chunk * KCHUNK;

  const unsigned long long* gseg8 =
      (const unsigned long long*)(seg + (size_t)b * HW_ + pbase);
  sseg8[threadIdx.x] = gseg8[threadIdx.x];
  __syncthreads();

  const int l = threadIdx.x & 63;
  const int w = threadIdx.x >> 6;
  const int lane31 = l & 31;
  const int hi = l >> 5;
  const int ch = w * 32 + lane31;

  const float* fp = feat + ((size_t)b * 128 + ch) * HW_ + pbase + hi * 8;
  const uint8_t* sp = (const uint8_t*)sseg8 + hi * 8;

  // packed 16-bit pair targets per M-tile: (m*32+lane31) in both halves
  unsigned tgt2[MT];
  #pragma unroll
  for (int m = 0; m < MT; ++m) {
    unsigned t = (unsigned)(m * 32 + lane31);
    tgt2[m] = t | (t << 16);
  }

  f32x16 acc[MT];
  #pragma unroll
  for (int m = 0; m < MT; ++m) acc[m] = (f32x16)(0.f);

  // 2-deep software pipeline
  float4 v0 = *(const float4*)(fp);
  float4 v1 = *(const float4*)(fp + 4);
  unsigned long long sb = *(const unsigned long long*)(sp);

  for (int k = 0; k < KSTEPS; ++k) {
    float4 nv0, nv1;
    unsigned long long nsb;
    if (k + 1 < KSTEPS) {
      nv0 = *(const float4*)(fp + (k + 1) * 16);
      nv1 = *(const float4*)(fp + (k + 1) * 16 + 4);
      nsb = *(const unsigned long long*)(sp + (k + 1) * 16);
    }

    // extract seg bytes as 4 dwords of packed u16 pairs
    unsigned svp[4];
    #pragma unroll
    for (int j = 0; j < 4; ++j) {
      unsigned lo8 = (unsigned)((sb >> (16 * j)) & 0xFFull);
      unsigned hi8 = (unsigned)((sb >> (16 * j + 8)) & 0xFFull);
      svp[j] = lo8 | (hi8 << 16);
    }

    // bf16 hi/lo split via v_cvt_pk_bf16_f32 (RNE)
    float fs[8] = {v0.x, v0.y, v0.z, v0.w, v1.x, v1.y, v1.z, v1.w};
    union { unsigned u[4]; short8v v; } bhi, blo;
    #pragma unroll
    for (int j = 0; j < 4; ++j) {
      float2v f2 = {fs[2 * j], fs[2 * j + 1]};
      bf16x2 h2 = __builtin_convertvector(f2, bf16x2);
      unsigned hb = __builtin_bit_cast(unsigned, h2);
      bhi.u[j] = hb;
      float fh0 = __builtin_bit_cast(float, hb << 16);
      float fh1 = __builtin_bit_cast(float, hb & 0xFFFF0000u);
      float2v l2 = {f2.x - fh0, f2.y - fh1};
      bf16x2 lo2 = __builtin_convertvector(l2, bf16x2);
      blo.u[j] = __builtin_bit_cast(unsigned, lo2);
    }

    #pragma unroll
    for (int m = 0; m < MT; ++m) {
      union { unsigned u[4]; short8v v; } a;
      #pragma unroll
      for (int j = 0; j < 4; ++j) {
        u16x2 y = __builtin_bit_cast(u16x2, svp[j] ^ tgt2[m]);
        u16x2 nz = __builtin_elementwise_min(y, (u16x2)(unsigned short)1);
        u16x2 msk = nz - (u16x2)(unsigned short)1;      // 0xFFFF on match
        u16x2 av = msk & (u16x2)(unsigned short)0x3F80; // bf16 1.0
        a.u[j] = __builtin_bit_cast(unsigned, av);
      }
      acc[m] =
          __builtin_amdgcn_mfma_f32_32x32x16_bf16(a.v, bhi.v, acc[m], 0, 0, 0);
      acc[m] =
          __builtin_amdgcn_mfma_f32_32x32x16_bf16(a.v, blo.v, acc[m], 0, 0, 0);
    }

    v0 = nv0; v1 = nv1; sb = nsb;
  }

  // epilogue: C/D layout col=lane&31, row=(reg&3)+8*(reg>>2)+4*(lane>>5)
  #pragma unroll
  for (int m = 0; m < MT; ++m) {
    #pragma unroll
    for (int r = 0; r < 16; ++r) {
      int s = m * 32 + (r & 3) + 8 * (r >> 2) + 4 * hi;
      float v = acc[m][r];
      if (v != 0.f)
        atomicAdd(&sums[((size_t)b * SEGS_PAD + s) * 128 + ch], v);
    }
  }
}

// ---------------- Pass 3: per-(image,class) pairwise loss ----------------
__global__ __launch_bounds__(256) void pairloss_kernel(
    const float* __restrict__ sums, const unsigned* __restrict__ counts,
    float* __restrict__ loss_sum, unsigned* __restrict__ nvalid, int D) {
  const int b = blockIdx.x / NC;
  const int c = blockIdx.x % NC;

  __shared__ float sh_mean[32 * 128];
  __shared__ float sh_cnt[IMAXP1];
  __shared__ int list[IMAXP1];
  __shared__ int Ksh;
  __shared__ uchar2 pairs[32 * 31 / 2];
  __shared__ double wred[4];

  if (threadIdx.x == 0) {
    int K = 0;
    for (int i = 1; i < IMAXP1; ++i) {   // slot 0 (ignore key) excluded
      unsigned cnt = counts[b * SEGS + c * IMAXP1 + i];
      if (cnt >= 2u) {                   // singleton segments excluded
        list[K] = i;
        sh_cnt[K] = (float)cnt;
        ++K;
      }
    }
    Ksh = K;
    int p = 0;
    for (int i = 0; i < K; ++i)
      for (int j = i + 1; j < K; ++j) {
        pairs[p].x = (unsigned char)i;
        pairs[p].y = (unsigned char)j;
        ++p;
      }
  }
  __syncthreads();
  const int K = Ksh;
  if (K == 0) return;

  for (int idx = threadIdx.x; idx < K * D; idx += blockDim.x) {
    int k = idx / 128, d = idx % 128;    // D==128
    int s = c * IMAXP1 + list[k];
    sh_mean[k * 128 + d] =
        sums[((size_t)b * SEGS_PAD + s) * D + d] / sh_cnt[k];
  }
  __syncthreads();

  const int npairs = K * (K - 1) / 2;
  const int total = npairs * 128;
  float local = 0.f;
  for (int idx = threadIdx.x; idx < total; idx += blockDim.x) {
    int p = idx >> 7, d = idx & 127;
    int i = pairs[p].x, j = pairs[p].y;
    local += fabsf(sh_mean[i * 128 + d] - sh_mean[j * 128 + d]);
  }

  double v = (double)local;
  #pragma unroll
  for (int off = 32; off; off >>= 1) v += __shfl_down(v, off, 64);
  const int wave = threadIdx.x >> 6;
  if ((threadIdx.x & 63) == 0) wred[wave] = v;
  __syncthreads();
  if (threadIdx.x == 0) {
    double ssum = 2.0 * (wred[0] + wred[1] + wred[2] + wred[3]);
    double ret = ssum / ((double)K * (double)K * (double)D);
    double loss = (ret < 1.0) ? 0.5 * ret * ret : ret - 0.5;
    atomicAdd(loss_sum, (float)loss);
    atomicAdd(nvalid, 1u);
  }
}

// ---------------- Pass 4: finalize ----------------
__global__ void finalize_kernel(const float* __restrict__ loss_sum,
                                const unsigned* __restrict__ nvalid,
                                float* __restrict__ out, int B) {
  if (threadIdx.x == 0) {
    unsigned n = *nvalid;
    out[0] = n ? (*loss_sum / (float)n) / (float)B : 0.f;
  }
}

extern "C" void kernel_launch(void* const* d_in, const int* in_sizes, int n_in,
                              void* d_out, int out_size, void* d_ws,
                              size_t ws_size, hipStream_t stream) {
  const float* feat = (const float*)d_in[0];
  const int* labels = (const int*)d_in[1];
  const int* indexes = (const int*)d_in[2];

  const int npix_total = in_sizes[1];          // B*H*W
  const int B = npix_total / HW_;              // 8
  const int D = in_sizes[0] / npix_total;      // 128

  // workspace: [seg bytes][sums f32 (SEGS_PAD)][counts u32][loss f32][n u32]
  uint8_t* seg = (uint8_t*)d_ws;
  size_t off = ((size_t)npix_total + 255) & ~(size_t)255;
  float* sums = (float*)((char*)d_ws + off);
  size_t sums_bytes = (size_t)B * SEGS_PAD * D * sizeof(float);
  unsigned* counts = (unsigned*)((char*)d_ws + off + sums_bytes);
  size_t counts_bytes = (size_t)B * SEGS * sizeof(unsigned);
  float* loss_sum = (float*)((char*)d_ws + off + sums_bytes + counts_bytes);
  unsigned* nvalid = (unsigned*)(loss_sum + 1);

  hipMemsetAsync(sums, 0, sums_bytes + counts_bytes + 2 * sizeof(unsigned),
                 stream);

  const int pix_per_block = 4096;
  seg_count_kernel<<<npix_total / pix_per_block, 256, 0, stream>>>(
      labels, indexes, seg, counts, pix_per_block);

  const int cpi = HW_ / KCHUNK;                // 128 chunks per image
  segsum_mfma_kernel<<<B * cpi, 256, 0, stream>>>(feat, seg, sums, cpi);

  pairloss_kernel<<<B * NC, 256, 0, stream>>>(sums, counts, loss_sum, nvalid,
                                              D);
  finalize_kernel<<<1, 64, 0, stream>>>(loss_sum, nvalid, (float*)d_out, B);
}

// Round 5
// 334.857 us; speedup vs baseline: 4.1810x; 1.1780x over previous
//
#include <hip/hip_runtime.h>
#include <stdint.h>

#define NC 5
#define IMAXP1 33
#define SEGS 165            // 5 * 33
#define SEGS_PAD 192        // 6 M-tiles of 32
#define MT 6
#define HW_ (512 * 512)
#define IGNORE_L 255
#define KCHUNK 2048         // pixels per segsum block
#define NSUP (KCHUNK / 64)  // 64-pixel supersteps (4 ksteps each)

typedef __attribute__((ext_vector_type(8))) short short8v;
typedef __attribute__((ext_vector_type(16))) float f32x16;
typedef __attribute__((ext_vector_type(2))) unsigned short u16x2;
typedef __attribute__((ext_vector_type(2))) float float2v;
typedef __attribute__((ext_vector_type(2))) __bf16 bf16x2;
typedef __attribute__((ext_vector_type(2))) unsigned long long u64x2;

// ---------------- Pass 1: seg ids + counts ----------------
__global__ __launch_bounds__(256) void seg_count_kernel(
    const int* __restrict__ labels, const int* __restrict__ indexes,
    uint8_t* __restrict__ seg, unsigned* __restrict__ counts,
    int pix_per_block) {
  __shared__ unsigned hist[SEGS];
  for (int i = threadIdx.x; i < SEGS; i += blockDim.x) hist[i] = 0u;
  __syncthreads();

  const long long base = (long long)blockIdx.x * pix_per_block;
  const int b = (int)(base / HW_);
  const int nvec = pix_per_block / 4;
  const int4* lab4 = (const int4*)(labels + base);
  const int4* idx4 = (const int4*)(indexes + base);
  uchar4* seg4 = (uchar4*)(seg + base);

  for (int k = threadIdx.x; k < nvec; k += blockDim.x) {
    int4 l = lab4[k];
    int4 ix = idx4[k];
    int s0 = (l.x == IGNORE_L) ? 0 : l.x * IMAXP1 + ix.x;
    int s1 = (l.y == IGNORE_L) ? 0 : l.y * IMAXP1 + ix.y;
    int s2 = (l.z == IGNORE_L) ? 0 : l.z * IMAXP1 + ix.z;
    int s3 = (l.w == IGNORE_L) ? 0 : l.w * IMAXP1 + ix.w;
    uchar4 sv;
    sv.x = (unsigned char)s0; sv.y = (unsigned char)s1;
    sv.z = (unsigned char)s2; sv.w = (unsigned char)s3;
    seg4[k] = sv;
    atomicAdd(&hist[s0], 1u);
    atomicAdd(&hist[s1], 1u);
    atomicAdd(&hist[s2], 1u);
    atomicAdd(&hist[s3], 1u);
  }
  __syncthreads();
  for (int i = threadIdx.x; i < SEGS; i += blockDim.x)
    if (hist[i]) atomicAdd(&counts[b * SEGS + i], hist[i]);
}

// ---------------- Pass 2: segment sums via one-hot MFMA GEMM ----------------
// sums[s,d] += sum_p onehot[s,p] * feat[p,d]; bf16 split-float (hi+lo) MFMA,
// f32 accumulation. Superstep = 64 pixels: each lane reads 128 B CONTIGUOUS
// (8x float4) of its channel row; A/B double-buffered one superstep ahead so
// ~1100 cycles of compute cover HBM latency, and per-channel DRAM streams
// advance in 256 B granules (row-buffer locality).
struct SS {
  float4 f[8];   // 32 px of this lane's channel
  u64x2 g0, g1;  // 32 seg bytes for those px
};

__global__ __launch_bounds__(256, 2) void segsum_mfma_kernel(
    const float* __restrict__ feat, const uint8_t* __restrict__ seg,
    float* __restrict__ sums, int chunks_per_img) {
  __shared__ unsigned long long sseg8[KCHUNK / 8];
  const int b = blockIdx.x / chunks_per_img;
  const int chunk = blockIdx.x % chunks_per_img;
  const int pbase = chunk * KCHUNK;

  const unsigned long long* gseg8 =
      (const unsigned long long*)(seg + (size_t)b * HW_ + pbase);
  sseg8[threadIdx.x] = gseg8[threadIdx.x];
  __syncthreads();

  const int l = threadIdx.x & 63;
  const int w = threadIdx.x >> 6;
  const int lane31 = l & 31;
  const int hi = l >> 5;
  const int ch = w * 32 + lane31;

  // lane's channel-row base: pixels pbase + hi*32, contiguous 128B/superstep
  const float4* fp4 =
      (const float4*)(feat + ((size_t)b * 128 + ch) * HW_ + pbase) + hi * 8;
  const uint8_t* sp = (const uint8_t*)sseg8 + hi * 32;

  const unsigned lane2 = (unsigned)lane31 | ((unsigned)lane31 << 16);

  f32x16 acc[MT];
  #pragma unroll
  for (int m = 0; m < MT; ++m) acc[m] = (f32x16)(0.f);

  #define LOAD_SS(dst, s)                                             \
    do {                                                              \
      _Pragma("unroll") for (int i = 0; i < 8; ++i)                   \
          (dst).f[i] = fp4[(size_t)(s)*16 + i];                       \
      const u64x2* sp2 = (const u64x2*)(sp + (s)*64);                 \
      (dst).g0 = sp2[0];                                              \
      (dst).g1 = sp2[1];                                              \
    } while (0)

  #define KSTEP(f0, f1, sb)                                           \
    do {                                                              \
      unsigned svp[4];                                                \
      _Pragma("unroll") for (int j = 0; j < 4; ++j) {                 \
        unsigned lo8 = (unsigned)(((sb) >> (16 * j)) & 0xFFull);      \
        unsigned hi8 = (unsigned)(((sb) >> (16 * j + 8)) & 0xFFull);  \
        svp[j] = (lo8 | (hi8 << 16)) ^ lane2;                         \
      }                                                               \
      float fs[8] = {(f0).x, (f0).y, (f0).z, (f0).w,                  \
                     (f1).x, (f1).y, (f1).z, (f1).w};                 \
      union { unsigned u[4]; short8v v; } bhi, blo;                   \
      _Pragma("unroll") for (int j = 0; j < 4; ++j) {                 \
        float2v f2 = {fs[2 * j], fs[2 * j + 1]};                      \
        bf16x2 h2 = __builtin_convertvector(f2, bf16x2);              \
        unsigned hb = __builtin_bit_cast(unsigned, h2);               \
        bhi.u[j] = hb;                                                \
        float fh0 = __builtin_bit_cast(float, hb << 16);              \
        float fh1 = __builtin_bit_cast(float, hb & 0xFFFF0000u);      \
        float2v l2 = {f2.x - fh0, f2.y - fh1};                        \
        bf16x2 lo2 = __builtin_convertvector(l2, bf16x2);             \
        blo.u[j] = __builtin_bit_cast(unsigned, lo2);                 \
      }                                                               \
      _Pragma("unroll") for (int m = 0; m < MT; ++m) {                \
        unsigned m2 = (unsigned)(m * 32) | ((unsigned)(m * 32) << 16);\
        union { unsigned u[4]; short8v v; } a;                        \
        _Pragma("unroll") for (int j = 0; j < 4; ++j) {               \
          u16x2 y = __builtin_bit_cast(u16x2, svp[j] ^ m2);           \
          u16x2 nz = __builtin_elementwise_min(y, (u16x2)(unsigned short)1); \
          u16x2 msk = nz - (u16x2)(unsigned short)1;                  \
          u16x2 av = msk & (u16x2)(unsigned short)0x3F80;             \
          a.u[j] = __builtin_bit_cast(unsigned, av);                  \
        }                                                             \
        acc[m] = __builtin_amdgcn_mfma_f32_32x32x16_bf16(a.v, bhi.v,  \
                                                         acc[m], 0, 0, 0); \
        acc[m] = __builtin_amdgcn_mfma_f32_32x32x16_bf16(a.v, blo.v,  \
                                                         acc[m], 0, 0, 0); \
      }                                                               \
    } while (0)

  #define COMPUTE_SS(src)                                             \
    do {                                                              \
      KSTEP((src).f[0], (src).f[1], (src).g0.x);                      \
      KSTEP((src).f[2], (src).f[3], (src).g0.y);                      \
      KSTEP((src).f[4], (src).f[5], (src).g1.x);                      \
      KSTEP((src).f[6], (src).f[7], (src).g1.y);                      \
    } while (0)

  SS bufA, bufB;
  LOAD_SS(bufA, 0);
  for (int s = 0; s < NSUP; s += 2) {
    LOAD_SS(bufB, s + 1);
    COMPUTE_SS(bufA);
    if (s + 2 < NSUP) LOAD_SS(bufA, s + 2);
    COMPUTE_SS(bufB);
  }

  // epilogue: C/D layout col=lane&31, row=(reg&3)+8*(reg>>2)+4*(lane>>5)
  #pragma unroll
  for (int m = 0; m < MT; ++m) {
    #pragma unroll
    for (int r = 0; r < 16; ++r) {
      int s = m * 32 + (r & 3) + 8 * (r >> 2) + 4 * hi;
      float v = acc[m][r];
      if (v != 0.f)
        atomicAdd(&sums[((size_t)b * SEGS_PAD + s) * 128 + ch], v);
    }
  }
}

// ---------------- Pass 3: per-(image,class) pairwise loss ----------------
__global__ __launch_bounds__(256) void pairloss_kernel(
    const float* __restrict__ sums, const unsigned* __restrict__ counts,
    float* __restrict__ loss_sum, unsigned* __restrict__ nvalid, int D) {
  const int b = blockIdx.x / NC;
  const int c = blockIdx.x % NC;

  __shared__ float sh_mean[32 * 128];
  __shared__ float sh_cnt[IMAXP1];
  __shared__ int list[IMAXP1];
  __shared__ int Ksh;
  __shared__ uchar2 pairs[32 * 31 / 2];
  __shared__ double wred[4];

  if (threadIdx.x == 0) {
    int K = 0;
    for (int i = 1; i < IMAXP1; ++i) {   // slot 0 (ignore key) excluded
      unsigned cnt = counts[b * SEGS + c * IMAXP1 + i];
      if (cnt >= 2u) {                   // singleton segments excluded
        list[K] = i;
        sh_cnt[K] = (float)cnt;
        ++K;
      }
    }
    Ksh = K;
    int p = 0;
    for (int i = 0; i < K; ++i)
      for (int j = i + 1; j < K; ++j) {
        pairs[p].x = (unsigned char)i;
        pairs[p].y = (unsigned char)j;
        ++p;
      }
  }
  __syncthreads();
  const int K = Ksh;
  if (K == 0) return;

  for (int idx = threadIdx.x; idx < K * D; idx += blockDim.x) {
    int k = idx / 128, d = idx % 128;    // D==128
    int s = c * IMAXP1 + list[k];
    sh_mean[k * 128 + d] =
        sums[((size_t)b * SEGS_PAD + s) * D + d] / sh_cnt[k];
  }
  __syncthreads();

  const int npairs = K * (K - 1) / 2;
  const int total = npairs * 128;
  float local = 0.f;
  for (int idx = threadIdx.x; idx < total; idx += blockDim.x) {
    int p = idx >> 7, d = idx & 127;
    int i = pairs[p].x, j = pairs[p].y;
    local += fabsf(sh_mean[i * 128 + d] - sh_mean[j * 128 + d]);
  }

  double v = (double)local;
  #pragma unroll
  for (int off = 32; off; off >>= 1) v += __shfl_down(v, off, 64);
  const int wave = threadIdx.x >> 6;
  if ((threadIdx.x & 63) == 0) wred[wave] = v;
  __syncthreads();
  if (threadIdx.x == 0) {
    double ssum = 2.0 * (wred[0] + wred[1] + wred[2] + wred[3]);
    double ret = ssum / ((double)K * (double)K * (double)D);
    double loss = (ret < 1.0) ? 0.5 * ret * ret : ret - 0.5;
    atomicAdd(loss_sum, (float)loss);
    atomicAdd(nvalid, 1u);
  }
}

// ---------------- Pass 4: finalize ----------------
__global__ void finalize_kernel(const float* __restrict__ loss_sum,
                                const unsigned* __restrict__ nvalid,
                                float* __restrict__ out, int B) {
  if (threadIdx.x == 0) {
    unsigned n = *nvalid;
    out[0] = n ? (*loss_sum / (float)n) / (float)B : 0.f;
  }
}

extern "C" void kernel_launch(void* const* d_in, const int* in_sizes, int n_in,
                              void* d_out, int out_size, void* d_ws,
                              size_t ws_size, hipStream_t stream) {
  const float* feat = (const float*)d_in[0];
  const int* labels = (const int*)d_in[1];
  const int* indexes = (const int*)d_in[2];

  const int npix_total = in_sizes[1];          // B*H*W
  const int B = npix_total / HW_;              // 8
  const int D = in_sizes[0] / npix_total;      // 128

  // workspace: [seg bytes][sums f32 (SEGS_PAD)][counts u32][loss f32][n u32]
  uint8_t* seg = (uint8_t*)d_ws;
  size_t off = ((size_t)npix_total + 255) & ~(size_t)255;
  float* sums = (float*)((char*)d_ws + off);
  size_t sums_bytes = (size_t)B * SEGS_PAD * D * sizeof(float);
  unsigned* counts = (unsigned*)((char*)d_ws + off + sums_bytes);
  size_t counts_bytes = (size_t)B * SEGS * sizeof(unsigned);
  float* loss_sum = (float*)((char*)d_ws + off + sums_bytes + counts_bytes);
  unsigned* nvalid = (unsigned*)(loss_sum + 1);

  hipMemsetAsync(sums, 0, sums_bytes + counts_bytes + 2 * sizeof(unsigned),
                 stream);

  const int pix_per_block = 4096;
  seg_count_kernel<<<npix_total / pix_per_block, 256, 0, stream>>>(
      labels, indexes, seg, counts, pix_per_block);

  const int cpi = HW_ / KCHUNK;                // 128 chunks per image
  segsum_mfma_kernel<<<B * cpi, 256, 0, stream>>>(feat, seg, sums, cpi);

  pairloss_kernel<<<B * NC, 256, 0, stream>>>(sums, counts, loss_sum, nvalid,
                                              D);
  finalize_kernel<<<1, 64, 0, stream>>>(loss_sum, nvalid, (float*)d_out, B);
}